// Round 1
// baseline (640.051 us; speedup 1.0000x reference)
//
#include <hip/hip_runtime.h>
#include <hip/hip_bf16.h>

#define DEVINL __device__ __forceinline__

typedef __attribute__((ext_vector_type(8))) short bf16x8;
typedef __attribute__((ext_vector_type(4))) float f32x4;

// f32 -> bf16 round-nearest-even (bit manipulation; values are finite)
DEVINL ushort f2bf(float f) {
  unsigned u = __float_as_uint(f);
  u += 0x7fffu + ((u >> 16) & 1u);
  return (ushort)(u >> 16);
}

DEVINL void gl_lds16(const void* g, void* lds) {
  __builtin_amdgcn_global_load_lds(
      (const __attribute__((address_space(1))) void*)g,
      (__attribute__((address_space(3))) void*)lds, 16, 0, 0);
}

DEVINL f32x4 mfma16(bf16x8 a, bf16x8 b, f32x4 c) {
  return __builtin_amdgcn_mfma_f32_16x16x32_bf16(a, b, c, 0, 0, 0);
}

// ======================= cast f32 -> bf16 =======================
__global__ __launch_bounds__(256) void cast_bf16_kernel(const float4* __restrict__ in,
                                                        ushort4* __restrict__ out, int n4) {
  int stride = (int)(gridDim.x * blockDim.x);
  for (int i = (int)(blockIdx.x * blockDim.x + threadIdx.x); i < n4; i += stride) {
    float4 v = in[i];
    out[i] = make_ushort4(f2bf(v.x), f2bf(v.y), f2bf(v.z), f2bf(v.w));
  }
}

// ======================= GEMM: C = A * Bm^T =======================
// A: M x K bf16 row-major. Bm: N x K bf16 row-major (nn.Linear weight).
// OUTMODE 0: C bf16 (M x N) row-major
// OUTMODE 1: C bf16 stored transposed per batch: Vt[(b*2048 + col)*2048 + t], row = b*2048 + t
// OUTMODE 2: C f32 + bias (final projection into d_out)
// 128x128 tile, BK=64, 4 waves, LDS staged in MFMA-fragment order (linear lane*16B reads).
template <int OUTMODE>
__global__ __launch_bounds__(256) void gemm_nt(const ushort* __restrict__ A,
                                               const ushort* __restrict__ Bm,
                                               void* __restrict__ Cout,
                                               const float* __restrict__ bias,
                                               int M, int N, int K) {
  __shared__ ushort Al[8192];  // [rb:8][ks:2][lane:64][8]
  __shared__ ushort Bl[8192];
  const int tid = (int)threadIdx.x;
  const int l = tid & 63, w = tid >> 6;
  const int wr = w >> 1, wc = w & 1;
  const int lr = l & 15, lg = l >> 4;
  const int rowT = (int)blockIdx.y * 128, colT = (int)blockIdx.x * 128;

  f32x4 acc[4][4] = {};

  for (int kt = 0; kt < K; kt += 64) {
#pragma unroll
    for (int q = 0; q < 4; ++q) {
      int s = q * 256 + tid;
      int rb = s >> 7, ks = (s >> 6) & 1, sl = s & 63;
      size_t koff = (size_t)(kt + ks * 32 + (sl >> 4) * 8);
      gl_lds16(A + (size_t)(rowT + rb * 16 + (sl & 15)) * K + koff,
               Al + (size_t)(q * 256 + (tid & 192)) * 8);
      gl_lds16(Bm + (size_t)(colT + rb * 16 + (sl & 15)) * K + koff,
               Bl + (size_t)(q * 256 + (tid & 192)) * 8);
    }
    __syncthreads();
#pragma unroll
    for (int ks = 0; ks < 2; ++ks) {
      bf16x8 af[4], bfv[4];
#pragma unroll
      for (int i = 0; i < 4; ++i) {
        af[i]  = *(const bf16x8*)(Al + (((wr * 4 + i) * 2 + ks) * 64 + l) * 8);
        bfv[i] = *(const bf16x8*)(Bl + (((wc * 4 + i) * 2 + ks) * 64 + l) * 8);
      }
#pragma unroll
      for (int i = 0; i < 4; ++i)
#pragma unroll
        for (int j = 0; j < 4; ++j)
          acc[i][j] = mfma16(af[i], bfv[j], acc[i][j]);
    }
    __syncthreads();
  }

  // C/D layout (measured, m89): col = lane&15, row = (lane>>4)*4 + reg
#pragma unroll
  for (int i = 0; i < 4; ++i) {
#pragma unroll
    for (int j = 0; j < 4; ++j) {
      const int col = colT + wc * 64 + j * 16 + lr;
#pragma unroll
      for (int e = 0; e < 4; ++e) {
        const int row = rowT + wr * 64 + i * 16 + lg * 4 + e;
        float v = acc[i][j][e];
        if (OUTMODE == 0) {
          ((ushort*)Cout)[(size_t)row * N + col] = f2bf(v);
        } else if (OUTMODE == 1) {
          ((ushort*)Cout)[((size_t)((row >> 11) * 2048 + col)) * 2048 + (row & 2047)] = f2bf(v);
        } else {
          ((float*)Cout)[(size_t)row * N + col] = v + bias[col];
        }
      }
    }
  }
}

// ======================= fused ALiBi attention =======================
// grid = (T/64 = 32 row-blocks, B*H = 32). 256 threads = 4 waves; wave owns 16 query rows.
// Pass 1: online (max,sum) over causal K-tiles. Pass 2: recompute scores, write normalized
// probs to attn output (f32), and accumulate P@V via MFMA (P round-trips LDS into A-frag order).
__global__ __launch_bounds__(256) void attn_kernel(const ushort* __restrict__ Qg,
                                                   const ushort* __restrict__ Kg,
                                                   const ushort* __restrict__ Vt,
                                                   float* __restrict__ attn_out,
                                                   ushort* __restrict__ Og) {
  __shared__ ushort Kl[8192];     // [cb:4][ks:4][lane:64][8]
  __shared__ ushort Vl[8192];     // [db:8][ks2:2][lane:64][8]
  __shared__ ushort Pl[4][1024];  // per-wave [ks2:2][lane:64][8]

  const int qb = (int)blockIdx.x, bh = (int)blockIdx.y;
  const int b = bh >> 4, h = bh & 15;
  const int tid = (int)threadIdx.x, l = tid & 63, w = tid >> 6;
  const int lr = l & 15, lg = l >> 4;
  const float scale = 0.08838834764831845f;      // 1/sqrt(128)
  const float slope = exp2f(-(float)(h + 1));    // alibi slope, H=16 power-of-2 path
  const int qr0 = qb * 64 + w * 16;

  // exact-zero fill of strictly-above-diagonal tiles of this 64-row stripe
  {
    const int r = tid >> 2, ci = tid & 3;
    float* rowp = attn_out + (size_t)(bh * 2048 + qb * 64 + r) * 2048;
    const float4 z = make_float4(0.f, 0.f, 0.f, 0.f);
    for (int c = (qb + 1) * 64 + ci * 4; c < 2048; c += 16)
      *(float4*)(rowp + c) = z;
  }

  // Q fragments held in registers for the whole kernel (A-operand; row = lane&15)
  bf16x8 qf[4];
#pragma unroll
  for (int ks = 0; ks < 4; ++ks)
    qf[ks] = *(const bf16x8*)(Qg + (size_t)(b * 2048 + qr0 + lr) * 2048 + h * 128 + ks * 32 + lg * 8);

  auto scores_tile = [&](int jt, f32x4* sc) {
#pragma unroll
    for (int cb = 0; cb < 4; ++cb) {
      f32x4 a = {};
#pragma unroll
      for (int ks = 0; ks < 4; ++ks) {
        bf16x8 kf = *(const bf16x8*)(Kl + ((cb * 4 + ks) * 64 + l) * 8);
        a = mfma16(qf[ks], kf, a);
      }
      const int kj = jt * 64 + cb * 16 + lr;
#pragma unroll
      for (int j = 0; j < 4; ++j) {
        const int qi = qr0 + lg * 4 + j;
        a[j] = (kj <= qi) ? a[j] * scale + slope * (float)(qi - kj) : -__builtin_inff();
      }
      sc[cb] = a;
    }
  };

  float runmax[4], runsum[4];
#pragma unroll
  for (int j = 0; j < 4; ++j) { runmax[j] = -__builtin_inff(); runsum[j] = 0.f; }

  // -------- pass 1: row stats --------
  for (int jt = 0; jt <= qb; ++jt) {
#pragma unroll
    for (int q = 0; q < 4; ++q) {
      int s = q * 256 + tid;
      int cb = s >> 8, ks = (s >> 6) & 3, sl = s & 63;
      gl_lds16(Kg + (size_t)(b * 2048 + jt * 64 + cb * 16 + (sl & 15)) * 2048 + h * 128 + ks * 32 + (sl >> 4) * 8,
               Kl + (size_t)(q * 256 + (tid & 192)) * 8);
    }
    __syncthreads();
    f32x4 sc[4];
    scores_tile(jt, sc);
#pragma unroll
    for (int j = 0; j < 4; ++j) {
      float m = fmaxf(fmaxf(sc[0][j], sc[1][j]), fmaxf(sc[2][j], sc[3][j]));
#pragma unroll
      for (int d = 1; d < 16; d <<= 1) m = fmaxf(m, __shfl_xor(m, d));
      const float nm = fmaxf(runmax[j], m);
      float sum = 0.f;
#pragma unroll
      for (int cb = 0; cb < 4; ++cb) sum += __expf(sc[cb][j] - nm);
#pragma unroll
      for (int d = 1; d < 16; d <<= 1) sum += __shfl_xor(sum, d);
      runsum[j] = runsum[j] * __expf(runmax[j] - nm) + sum;
      runmax[j] = nm;
    }
    __syncthreads();
  }

  float inv[4];
#pragma unroll
  for (int j = 0; j < 4; ++j) inv[j] = 1.f / runsum[j];

  f32x4 o[8] = {};  // PV accumulator: col = db*16 + (lane&15), row = (lane>>4)*4 + reg

  // -------- pass 2: probs + PV --------
  for (int jt = 0; jt <= qb; ++jt) {
#pragma unroll
    for (int q = 0; q < 4; ++q) {
      int s = q * 256 + tid;
      int cb = s >> 8, ks = (s >> 6) & 3, sl = s & 63;
      gl_lds16(Kg + (size_t)(b * 2048 + jt * 64 + cb * 16 + (sl & 15)) * 2048 + h * 128 + ks * 32 + (sl >> 4) * 8,
               Kl + (size_t)(q * 256 + (tid & 192)) * 8);
      int db = s >> 7, ks2 = (s >> 6) & 1;
      gl_lds16(Vt + (size_t)(b * 2048 + h * 128 + db * 16 + (sl & 15)) * 2048 + jt * 64 + ks2 * 32 + (sl >> 4) * 8,
               Vl + (size_t)(q * 256 + (tid & 192)) * 8);
    }
    __syncthreads();
    f32x4 sc[4];
    scores_tile(jt, sc);
#pragma unroll
    for (int cb = 0; cb < 4; ++cb) {
      const int kc = cb * 16 + lr;   // key col within 64-tile
      const int kj = jt * 64 + kc;
#pragma unroll
      for (int j = 0; j < 4; ++j) {
        const int qi = qr0 + lg * 4 + j;
        const float p = __expf(sc[cb][j] - runmax[j]) * inv[j];
        attn_out[(size_t)(bh * 2048 + qi) * 2048 + kj] = p;
        // scatter into per-wave A-fragment order: row=q_r in lane&15, k=kc via same slot map
        const int l2 = (((kc & 31) >> 3) << 4) | (lg * 4 + j);
        Pl[w][((kc >> 5) * 64 + l2) * 8 + (kc & 7)] = f2bf(p);
      }
    }
    // wave-local LDS RAW: compiler inserts lgkmcnt waits (no barrier needed within wave)
#pragma unroll
    for (int db = 0; db < 8; ++db) {
#pragma unroll
      for (int ks2 = 0; ks2 < 2; ++ks2) {
        bf16x8 pf = *(const bf16x8*)(&Pl[w][(ks2 * 64 + l) * 8]);
        bf16x8 vf = *(const bf16x8*)(Vl + ((db * 2 + ks2) * 64 + l) * 8);
        o[db] = mfma16(pf, vf, o[db]);
      }
    }
    __syncthreads();
  }

#pragma unroll
  for (int db = 0; db < 8; ++db)
#pragma unroll
    for (int j = 0; j < 4; ++j)
      Og[(size_t)(b * 2048 + qr0 + lg * 4 + j) * 2048 + h * 128 + db * 16 + lr] = f2bf(o[db][j]);
}

// ======================= launch =======================
extern "C" void kernel_launch(void* const* d_in, const int* in_sizes, int n_in,
                              void* d_out, int out_size, void* d_ws, size_t ws_size,
                              hipStream_t stream) {
  (void)in_sizes; (void)n_in; (void)out_size; (void)ws_size;
  const float* x  = (const float*)d_in[0];
  const float* Wq = (const float*)d_in[1];
  const float* Wk = (const float*)d_in[2];
  const float* Wv = (const float*)d_in[3];
  const float* Wo = (const float*)d_in[4];
  const float* bo = (const float*)d_in[5];

  float* outp  = (float*)d_out;                      // (B,T,C) = 8,388,608 f32
  float* attnp = outp + (size_t)4096 * 2048;         // (B,H,T,T) = 134,217,728 f32

  char* ws = (char*)d_ws;                            // 112 MB used
  ushort* xb  = (ushort*)(ws);                       // x bf16      (16 MB)
  ushort* wqb = (ushort*)(ws + (16ull << 20));       // Wq bf16     (8 MB)
  ushort* wkb = (ushort*)(ws + (24ull << 20));
  ushort* wvb = (ushort*)(ws + (32ull << 20));
  ushort* wob = (ushort*)(ws + (40ull << 20));
  ushort* Qb  = (ushort*)(ws + (48ull << 20));       // Q bf16      (16 MB)
  ushort* Kb  = (ushort*)(ws + (64ull << 20));       // K bf16      (16 MB)
  ushort* Vtb = (ushort*)(ws + (80ull << 20));       // V^T bf16    (16 MB)
  ushort* Ob  = (ushort*)(ws + (96ull << 20));       // attn@V bf16 (16 MB)

  cast_bf16_kernel<<<2048, 256, 0, stream>>>((const float4*)x,  (ushort4*)xb,  8388608 / 4);
  cast_bf16_kernel<<<1024, 256, 0, stream>>>((const float4*)Wq, (ushort4*)wqb, 4194304 / 4);
  cast_bf16_kernel<<<1024, 256, 0, stream>>>((const float4*)Wk, (ushort4*)wkb, 4194304 / 4);
  cast_bf16_kernel<<<1024, 256, 0, stream>>>((const float4*)Wv, (ushort4*)wvb, 4194304 / 4);
  cast_bf16_kernel<<<1024, 256, 0, stream>>>((const float4*)Wo, (ushort4*)wob, 4194304 / 4);

  dim3 g(16, 32);  // N/128, M/128
  gemm_nt<0><<<g, 256, 0, stream>>>(xb, wqb, Qb,  nullptr, 4096, 2048, 2048);
  gemm_nt<0><<<g, 256, 0, stream>>>(xb, wkb, Kb,  nullptr, 4096, 2048, 2048);
  gemm_nt<1><<<g, 256, 0, stream>>>(xb, wvb, Vtb, nullptr, 4096, 2048, 2048);

  attn_kernel<<<dim3(32, 32), 256, 0, stream>>>(Qb, Kb, Vtb, attnp, Ob);

  gemm_nt<2><<<g, 256, 0, stream>>>(Ob, wob, outp, bo, 4096, 2048, 2048);
}

// Round 2
// 568.568 us; speedup vs baseline: 1.1257x; 1.1257x over previous
//
#include <hip/hip_runtime.h>
#include <hip/hip_bf16.h>

#define DEVINL __device__ __forceinline__

typedef __attribute__((ext_vector_type(8))) short bf16x8;
typedef __attribute__((ext_vector_type(4))) float f32x4;

// f32 -> bf16 round-nearest-even (bit manipulation; values are finite)
DEVINL ushort f2bf(float f) {
  unsigned u = __float_as_uint(f);
  u += 0x7fffu + ((u >> 16) & 1u);
  return (ushort)(u >> 16);
}

DEVINL void gl_lds16(const void* g, void* lds) {
  __builtin_amdgcn_global_load_lds(
      (const __attribute__((address_space(1))) void*)g,
      (__attribute__((address_space(3))) void*)lds, 16, 0, 0);
}

DEVINL f32x4 mfma16(bf16x8 a, bf16x8 b, f32x4 c) {
  return __builtin_amdgcn_mfma_f32_16x16x32_bf16(a, b, c, 0, 0, 0);
}

// ======================= cast f32 -> bf16 =======================
__global__ __launch_bounds__(256) void cast_bf16_kernel(const float4* __restrict__ in,
                                                        ushort4* __restrict__ out, int n4) {
  int stride = (int)(gridDim.x * blockDim.x);
  for (int i = (int)(blockIdx.x * blockDim.x + threadIdx.x); i < n4; i += stride) {
    float4 v = in[i];
    out[i] = make_ushort4(f2bf(v.x), f2bf(v.y), f2bf(v.z), f2bf(v.w));
  }
}

// ======================= GEMM: C = A * Bm^T =======================
// A: M x K bf16 row-major. Bm: N x K bf16 row-major (nn.Linear weight).
// OUTMODE 0: C bf16 (M x N) row-major
// OUTMODE 1: C bf16 stored transposed per batch: Vt[(b*2048 + col)*2048 + t]
// OUTMODE 2: C f32 + bias (final projection into d_out)
template <int OUTMODE>
__global__ __launch_bounds__(256) void gemm_nt(const ushort* __restrict__ A,
                                               const ushort* __restrict__ Bm,
                                               void* __restrict__ Cout,
                                               const float* __restrict__ bias,
                                               int M, int N, int K) {
  __shared__ __align__(16) ushort Al[8192];  // [rb:8][ks:2][lane:64][8]
  __shared__ __align__(16) ushort Bl[8192];
  const int tid = (int)threadIdx.x;
  const int l = tid & 63, w = tid >> 6;
  const int wr = w >> 1, wc = w & 1;
  const int lr = l & 15, lg = l >> 4;
  const int rowT = (int)blockIdx.y * 128, colT = (int)blockIdx.x * 128;

  f32x4 acc[4][4] = {};

  for (int kt = 0; kt < K; kt += 64) {
#pragma unroll
    for (int q = 0; q < 4; ++q) {
      int s = q * 256 + tid;
      int rb = s >> 7, ks = (s >> 6) & 1, sl = s & 63;
      size_t koff = (size_t)(kt + ks * 32 + (sl >> 4) * 8);
      gl_lds16(A + (size_t)(rowT + rb * 16 + (sl & 15)) * K + koff,
               Al + (size_t)(q * 256 + (tid & 192)) * 8);
      gl_lds16(Bm + (size_t)(colT + rb * 16 + (sl & 15)) * K + koff,
               Bl + (size_t)(q * 256 + (tid & 192)) * 8);
    }
    __syncthreads();
#pragma unroll
    for (int ks = 0; ks < 2; ++ks) {
      bf16x8 af[4], bfv[4];
#pragma unroll
      for (int i = 0; i < 4; ++i) {
        af[i]  = *(const bf16x8*)(Al + (((wr * 4 + i) * 2 + ks) * 64 + l) * 8);
        bfv[i] = *(const bf16x8*)(Bl + (((wc * 4 + i) * 2 + ks) * 64 + l) * 8);
      }
#pragma unroll
      for (int i = 0; i < 4; ++i)
#pragma unroll
        for (int j = 0; j < 4; ++j)
          acc[i][j] = mfma16(af[i], bfv[j], acc[i][j]);
    }
    __syncthreads();
  }

  // C/D layout (measured, m89): col = lane&15, row = (lane>>4)*4 + reg
#pragma unroll
  for (int i = 0; i < 4; ++i) {
#pragma unroll
    for (int j = 0; j < 4; ++j) {
      const int col = colT + wc * 64 + j * 16 + lr;
#pragma unroll
      for (int e = 0; e < 4; ++e) {
        const int row = rowT + wr * 64 + i * 16 + lg * 4 + e;
        float v = acc[i][j][e];
        if (OUTMODE == 0) {
          ((ushort*)Cout)[(size_t)row * N + col] = f2bf(v);
        } else if (OUTMODE == 1) {
          ((ushort*)Cout)[((size_t)((row >> 11) * 2048 + col)) * 2048 + (row & 2047)] = f2bf(v);
        } else {
          ((float*)Cout)[(size_t)row * N + col] = v + bias[col];
        }
      }
    }
  }
}

// ======================= flash kernel: O + row stats =======================
// grid (16, 32): block processes q-tiles {31-bx, bx} (constant 33 K-tiles -> balanced).
// 4 waves, wave owns 16 q-rows. Double-buffered K/V staging (2-phase template:
// stage next tile, compute current, single vmcnt(0)+barrier per tile).
// jt descends from diagonal so running max settles immediately (rescale branch cold).
__global__ __launch_bounds__(256) void flash_kernel(const ushort* __restrict__ Qg,
                                                    const ushort* __restrict__ Kg,
                                                    const ushort* __restrict__ Vt,
                                                    ushort* __restrict__ Og,
                                                    float2* __restrict__ stats) {
  __shared__ __align__(16) ushort Kl[2][8192];
  __shared__ __align__(16) ushort Vl[2][8192];
  __shared__ __align__(16) ushort Pl[4][1024];

  // XCD-chunked swizzle: 512 blocks, 512%8==0 -> each XCD gets 4 heads' worth (L2-fit)
  const int flat = (int)(blockIdx.y * gridDim.x + blockIdx.x);
  const int swz = (flat & 7) * 64 + (flat >> 3);
  const int bx = swz & 15, bh = swz >> 4;
  const int b = bh >> 4, h = bh & 15;
  const int tid = (int)threadIdx.x, l = tid & 63, w = tid >> 6;
  const int lr = l & 15, lg = l >> 4;
  const float scale = 0.08838834764831845f;    // 1/sqrt(128)
  const float slope = exp2f(-(float)(h + 1));  // alibi slope
  const ushort* Kbase = Kg + ((size_t)b * 2048) * 2048 + h * 128;
  const ushort* Vbase = Vt + ((size_t)b * 2048 + h * 128) * 2048;

  for (int half = 0; half < 2; ++half) {
    const int qb = (half == 0) ? 31 - bx : bx;
    const int qr0 = qb * 64 + w * 16;

    bf16x8 qf[4];
#pragma unroll
    for (int ks = 0; ks < 4; ++ks)
      qf[ks] = *(const bf16x8*)(Qg + ((size_t)b * 2048 + qr0 + lr) * 2048 + h * 128 + ks * 32 + lg * 8);

    float runmax[4], runsum[4];
    f32x4 o[8] = {};
#pragma unroll
    for (int j = 0; j < 4; ++j) { runmax[j] = -__builtin_inff(); runsum[j] = 0.f; }

    auto stage = [&](int jt, int buf) {
#pragma unroll
      for (int q = 0; q < 4; ++q) {
        const int s = q * 256 + tid;
        const int sl = s & 63;
        const int cb = s >> 8, ks = (s >> 6) & 3;
        gl_lds16(Kbase + (size_t)(jt * 64 + cb * 16 + (sl & 15)) * 2048 + ks * 32 + (sl >> 4) * 8,
                 &Kl[buf][(size_t)(q * 256 + (tid & 192)) * 8]);
        const int db = s >> 7, k2 = (s >> 6) & 1;
        gl_lds16(Vbase + (size_t)(db * 16 + (sl & 15)) * 2048 + jt * 64 + k2 * 32 + (sl >> 4) * 8,
                 &Vl[buf][(size_t)(q * 256 + (tid & 192)) * 8]);
      }
    };

    stage(qb, 0);
    __syncthreads();

    for (int jt = qb; jt >= 0; --jt) {
      const int cur = (qb - jt) & 1;
      if (jt > 0) stage(jt - 1, cur ^ 1);

      // QK^T + bias/mask
      f32x4 sc[4];
#pragma unroll
      for (int cb = 0; cb < 4; ++cb) {
        f32x4 a = {};
#pragma unroll
        for (int ks = 0; ks < 4; ++ks) {
          bf16x8 kf = *(const bf16x8*)(&Kl[cur][((cb * 4 + ks) * 64 + l) * 8]);
          a = mfma16(qf[ks], kf, a);
        }
        const int kj = jt * 64 + cb * 16 + lr;
#pragma unroll
        for (int j = 0; j < 4; ++j) {
          const int qi = qr0 + lg * 4 + j;
          a[j] = (kj <= qi) ? a[j] * scale + slope * (float)(qi - kj) : -__builtin_inff();
        }
        sc[cb] = a;
      }

      // online max (16-lane reduce per row); rescale rarely fires (descending jt)
      float nm[4];
      bool need = false;
#pragma unroll
      for (int j = 0; j < 4; ++j) {
        float m = fmaxf(fmaxf(sc[0][j], sc[1][j]), fmaxf(sc[2][j], sc[3][j]));
#pragma unroll
        for (int d = 1; d < 16; d <<= 1) m = fmaxf(m, __shfl_xor(m, d));
        nm[j] = fmaxf(runmax[j], m);
        need = need || (nm[j] > runmax[j]);
      }
      if (__any(need)) {
#pragma unroll
        for (int j = 0; j < 4; ++j) {
          const float f = __expf(runmax[j] - nm[j]);  // 0 on first tile, 1 if no growth
          runsum[j] *= f;
#pragma unroll
          for (int db = 0; db < 8; ++db) o[db][j] *= f;
          runmax[j] = nm[j];
        }
      }

      // p = exp(s - m); lane-partial row sums (reduced once at the end)
#pragma unroll
      for (int cb = 0; cb < 4; ++cb) {
        const int kc = cb * 16 + lr;
#pragma unroll
        for (int j = 0; j < 4; ++j) {
          const float p = __expf(sc[cb][j] - runmax[j]);
          runsum[j] += p;
          const int l2 = (((kc & 31) >> 3) << 4) | (lg * 4 + j);
          Pl[w][((kc >> 5) * 64 + l2) * 8 + (kc & 7)] = f2bf(p);
        }
      }

      // PV (P round-trips per-wave LDS into A-fragment order; wave-local lgkmcnt)
      bf16x8 pf0 = *(const bf16x8*)(&Pl[w][(size_t)l * 8]);
      bf16x8 pf1 = *(const bf16x8*)(&Pl[w][(size_t)(64 + l) * 8]);
#pragma unroll
      for (int db = 0; db < 8; ++db) {
        o[db] = mfma16(pf0, *(const bf16x8*)(&Vl[cur][((db * 2 + 0) * 64 + l) * 8]), o[db]);
        o[db] = mfma16(pf1, *(const bf16x8*)(&Vl[cur][((db * 2 + 1) * 64 + l) * 8]), o[db]);
      }
      __syncthreads();  // drains stage loads for next tile; guards buffer reuse
    }

    // finalize: reduce row sums, write stats + O
#pragma unroll
    for (int j = 0; j < 4; ++j) {
      float s = runsum[j];
#pragma unroll
      for (int d = 1; d < 16; d <<= 1) s += __shfl_xor(s, d);
      const float iv = 1.0f / s;
      if (lr == 0) stats[(size_t)bh * 2048 + qr0 + lg * 4 + j] = make_float2(runmax[j], iv);
#pragma unroll
      for (int db = 0; db < 8; ++db) o[db][j] *= iv;
    }
#pragma unroll
    for (int db = 0; db < 8; ++db)
#pragma unroll
      for (int j = 0; j < 4; ++j)
        Og[((size_t)b * 2048 + qr0 + lg * 4 + j) * 2048 + h * 128 + db * 16 + lr] = f2bf(o[db][j]);
  }
}

// ======================= probs kernel: write attn matrix =======================
// grid (16 kb, 16 qb, 32 bh). kb>qb: pure zero-fill. Else 128x128 Q@K^T tile (K=128,
// single-shot LDS) with epilogue p = exp(s - m)*inv. MFMA order matches flash -> s<=m.
__global__ __launch_bounds__(256) void probs_kernel(const ushort* __restrict__ Qg,
                                                    const ushort* __restrict__ Kg,
                                                    const float2* __restrict__ stats,
                                                    float* __restrict__ attn_out) {
  const int kb = (int)blockIdx.x, qb = (int)blockIdx.y, bh = (int)blockIdx.z;
  const int tid = (int)threadIdx.x;

  if (kb > qb) {  // strictly-above-diagonal tile: exact zeros
    float* base = attn_out + ((size_t)bh * 2048 + qb * 128) * 2048 + kb * 128;
    const float4 z = make_float4(0.f, 0.f, 0.f, 0.f);
#pragma unroll
    for (int it = 0; it < 16; ++it) {
      const int idx = it * 256 + tid;
      *(float4*)(base + (size_t)(idx >> 5) * 2048 + (idx & 31) * 4) = z;
    }
    return;
  }

  __shared__ __align__(16) ushort Ql[16384];  // 128 rows x 128 k, fragment order
  __shared__ __align__(16) ushort Kl[16384];
  const int b = bh >> 4, h = bh & 15;
  const int l = tid & 63, w = tid >> 6;
  const int wr = w >> 1, wc = w & 1;
  const int lr = l & 15, lg = l >> 4;
  const float scale = 0.08838834764831845f;
  const float slope = exp2f(-(float)(h + 1));

#pragma unroll
  for (int q = 0; q < 8; ++q) {
    const int s = q * 256 + tid;
    const int sl = s & 63, rb = s >> 8, ks = (s >> 6) & 3;
    const size_t koff = (size_t)(h * 128 + ks * 32 + (sl >> 4) * 8);
    gl_lds16(Qg + ((size_t)b * 2048 + qb * 128 + rb * 16 + (sl & 15)) * 2048 + koff,
             Ql + (size_t)(q * 256 + (tid & 192)) * 8);
    gl_lds16(Kg + ((size_t)b * 2048 + kb * 128 + rb * 16 + (sl & 15)) * 2048 + koff,
             Kl + (size_t)(q * 256 + (tid & 192)) * 8);
  }
  __syncthreads();

  f32x4 acc[4][4] = {};
#pragma unroll
  for (int ks = 0; ks < 4; ++ks) {
    bf16x8 af[4], bfv[4];
#pragma unroll
    for (int i = 0; i < 4; ++i) {
      af[i]  = *(const bf16x8*)(Ql + (((wr * 4 + i) * 4 + ks) * 64 + l) * 8);
      bfv[i] = *(const bf16x8*)(Kl + (((wc * 4 + i) * 4 + ks) * 64 + l) * 8);
    }
#pragma unroll
    for (int i = 0; i < 4; ++i)
#pragma unroll
      for (int j = 0; j < 4; ++j)
        acc[i][j] = mfma16(af[i], bfv[j], acc[i][j]);
  }

  float2 st[4][4];
#pragma unroll
  for (int i = 0; i < 4; ++i)
#pragma unroll
    for (int e = 0; e < 4; ++e)
      st[i][e] = stats[(size_t)bh * 2048 + qb * 128 + wr * 64 + i * 16 + lg * 4 + e];

#pragma unroll
  for (int i = 0; i < 4; ++i) {
#pragma unroll
    for (int j = 0; j < 4; ++j) {
      const int kj = kb * 128 + wc * 64 + j * 16 + lr;
#pragma unroll
      for (int e = 0; e < 4; ++e) {
        const int qi = qb * 128 + wr * 64 + i * 16 + lg * 4 + e;
        const float sv = acc[i][j][e] * scale + slope * (float)(qi - kj);
        float p = __expf(sv - st[i][e].x) * st[i][e].y;
        if (kj > qi) p = 0.f;  // only possible when kb == qb
        attn_out[((size_t)bh * 2048 + qi) * 2048 + kj] = p;
      }
    }
  }
}

// ======================= launch =======================
extern "C" void kernel_launch(void* const* d_in, const int* in_sizes, int n_in,
                              void* d_out, int out_size, void* d_ws, size_t ws_size,
                              hipStream_t stream) {
  (void)in_sizes; (void)n_in; (void)out_size; (void)ws_size;
  const float* x  = (const float*)d_in[0];
  const float* Wq = (const float*)d_in[1];
  const float* Wk = (const float*)d_in[2];
  const float* Wv = (const float*)d_in[3];
  const float* Wo = (const float*)d_in[4];
  const float* bo = (const float*)d_in[5];

  float* outp  = (float*)d_out;                      // (B,T,C) f32
  float* attnp = outp + (size_t)4096 * 2048;         // (B,H,T,T) f32

  char* ws = (char*)d_ws;                            // 112 MB used
  ushort* xb  = (ushort*)(ws);                       // x bf16      (16 MB)
  ushort* wqb = (ushort*)(ws + (16ull << 20));       // Wq bf16     (8 MB)
  ushort* wkb = (ushort*)(ws + (24ull << 20));
  ushort* wvb = (ushort*)(ws + (32ull << 20));
  ushort* wob = (ushort*)(ws + (40ull << 20));
  ushort* Qb  = (ushort*)(ws + (48ull << 20));       // Q bf16      (16 MB)
  ushort* Kb  = (ushort*)(ws + (64ull << 20));       // K bf16      (16 MB)
  ushort* Vtb = (ushort*)(ws + (80ull << 20));       // V^T bf16    (16 MB)
  ushort* Ob  = (ushort*)(ws + (96ull << 20));       // attn@V bf16 (16 MB)
  // stats (m, 1/sum) per row: 512 KB. Reuses the xb region — xb is dead after the
  // QKV GEMMs, and is rewritten by the cast at the start of every call (deterministic).
  float2* stats = (float2*)(ws);

  cast_bf16_kernel<<<2048, 256, 0, stream>>>((const float4*)x,  (ushort4*)xb,  8388608 / 4);
  cast_bf16_kernel<<<1024, 256, 0, stream>>>((const float4*)Wq, (ushort4*)wqb, 4194304 / 4);
  cast_bf16_kernel<<<1024, 256, 0, stream>>>((const float4*)Wk, (ushort4*)wkb, 4194304 / 4);
  cast_bf16_kernel<<<1024, 256, 0, stream>>>((const float4*)Wv, (ushort4*)wvb, 4194304 / 4);
  cast_bf16_kernel<<<1024, 256, 0, stream>>>((const float4*)Wo, (ushort4*)wob, 4194304 / 4);

  dim3 g(16, 32);  // N/128, M/128
  gemm_nt<0><<<g, 256, 0, stream>>>(xb, wqb, Qb,  nullptr, 4096, 2048, 2048);
  gemm_nt<0><<<g, 256, 0, stream>>>(xb, wkb, Kb,  nullptr, 4096, 2048, 2048);
  gemm_nt<1><<<g, 256, 0, stream>>>(xb, wvb, Vtb, nullptr, 4096, 2048, 2048);

  flash_kernel<<<dim3(16, 32), 256, 0, stream>>>(Qb, Kb, Vtb, Ob, stats);
  probs_kernel<<<dim3(16, 16, 32), 256, 0, stream>>>(Qb, Kb, stats, attnp);

  gemm_nt<2><<<g, 256, 0, stream>>>(Ob, wob, outp, bo, 4096, 2048, 2048);
}